// Round 12
// baseline (383.955 us; speedup 1.0000x reference)
//
#include <hip/hip_runtime.h>

typedef unsigned short ushort_t;
typedef unsigned int uint_t;
typedef __attribute__((ext_vector_type(8))) short short8;
typedef __attribute__((ext_vector_type(4))) float f32x4;

__device__ __forceinline__ float bf2f(ushort_t u) {
    union { unsigned u; float f; } c; c.u = ((unsigned)u) << 16; return c.f;
}
__device__ __forceinline__ ushort_t f2bf(float f) {
    union { float f; unsigned u; } c; c.f = f;
    unsigned u = c.u;
    u += 0x7fffu + ((u >> 16) & 1u);   // RNE
    return (ushort_t)(u >> 16);
}
__device__ __forceinline__ float2 upk(uint_t u) {
    float2 r; r.x = bf2f((ushort_t)(u & 0xffffu)); r.y = bf2f((ushort_t)(u >> 16));
    return r;
}

// ---------------------------------------------------------------------------
// PREP (fused, independent sections partitioned by blockIdx):
//   [0, cvtB)              : x fp32 -> bf16 (2 elems/thread)
//   [cvtB, cvtB+initB)     : zero deg[N+1] + stats[512] + pooled[G*128]
//   [+initB, +initB+256)   : pack 4 weight matrices into MFMA B-frag bf16
//   [.., +G)               : code-branch per-graph MLP + log_softmax
// ---------------------------------------------------------------------------
__global__ __launch_bounds__(256) void prep(
    const float2* __restrict__ x2, uint_t* __restrict__ xbf, int n2, int cvtB,
    int* __restrict__ deg, int ni, float* __restrict__ stats0,
    float* __restrict__ pool0, int np, int initB,
    const float* __restrict__ w0, const float* __restrict__ w1,
    const float* __restrict__ w2, const float* __restrict__ w3,
    ushort_t* __restrict__ packW,
    const float* __restrict__ cx,
    const float* __restrict__ cw1, const float* __restrict__ cb1,
    const float* __restrict__ cw2, const float* __restrict__ cb2,
    const float* __restrict__ cw3, const float* __restrict__ cb3,
    float* __restrict__ code_emb) {
    __shared__ float xb[128], h[128];
    int blk = blockIdx.x, tid = threadIdx.x;

    if (blk < cvtB) {                      // ---- cvt ----
        int i = blk * 256 + tid;
        if (i < n2) {
            float2 v = x2[i];
            xbf[i] = (uint_t)f2bf(v.x) | ((uint_t)f2bf(v.y) << 16);
        }
        return;
    }
    blk -= cvtB;
    if (blk < initB) {                     // ---- init ----
        int i = blk * 256 + tid;
        if (i < ni) deg[i] = 0;
        if (i < 512) stats0[i] = 0.f;
        if (i < np) pool0[i] = 0.f;
        return;
    }
    blk -= initB;
    if (blk < 256) {                       // ---- pack_w ----
        int id = blk * 256 + tid;          // 4*16384 total
        int m = id >> 14, r = id & 16383;
        const float* w = (m == 0) ? w0 : (m == 1) ? w1 : (m == 2) ? w2 : w3;
        int i = r & 7, lane = (r >> 3) & 63, ct = (r >> 9) & 7, ch = r >> 12;
        int k = ch * 32 + ((lane >> 4) << 3) + i;
        int n = ct * 16 + (lane & 15);
        packW[m * 16384 + r] = f2bf(w[k * 128 + n]);
        return;
    }
    blk -= 256;
    {                                      // ---- code branch (g = blk) ----
        int g = blk, j = tid;
        if (j < 128) xb[j] = cx[(size_t)g * 128 + j];
        __syncthreads();
        float acc = 0.f;
        if (j < 128) {
            acc = cb1[j];
            for (int k = 0; k < 128; ++k) acc += xb[k] * cw1[k * 128 + j];
        }
        __syncthreads();
        if (j < 128) h[j] = fmaxf(acc, 0.f);
        __syncthreads();
        if (j < 128) {
            acc = cb2[j];
            for (int k = 0; k < 128; ++k) acc += h[k] * cw2[k * 128 + j];
        }
        __syncthreads();
        if (j < 128) xb[j] = fmaxf(acc, 0.f);
        __syncthreads();
        if (j < 64) {
            float o = cb3[j];
            for (int k = 0; k < 128; ++k) o += xb[k] * cw3[k * 64 + j];
            float m = o;
            for (int off = 32; off; off >>= 1) m = fmaxf(m, __shfl_xor(m, off));
            float e = expf(o - m), s = e;
            for (int off = 32; off; off >>= 1) s += __shfl_xor(s, off);
            float lse = m + logf(s);
            code_emb[(size_t)g * 64 + j] = o - lse;
        }
    }
}

// ---------------------------------------------------------------------------
// CSR build: histogram -> per-chunk scan -> (scan bsum + apply, merged) ->
// scatter
// ---------------------------------------------------------------------------
__global__ void hist_dst(const int* __restrict__ dst, int* __restrict__ deg, int E) {
    int e = blockIdx.x * blockDim.x + threadIdx.x;
    if (e < E) atomicAdd(&deg[dst[e]], 1);
}

__global__ void scan1(const int* __restrict__ deg, int* __restrict__ rowptr,
                      int* __restrict__ bsum, int N) {
    __shared__ int sh[256];
    int t = threadIdx.x, idx = blockIdx.x * 256 + t;
    sh[t] = (idx < N) ? deg[idx] : 0;
    __syncthreads();
    for (int off = 1; off < 256; off <<= 1) {
        int v = (t >= off) ? sh[t - off] : 0;
        __syncthreads();
        sh[t] += v;
        __syncthreads();
    }
    if (idx < N) rowptr[idx + 1] = sh[t];
    if (t == 255) bsum[blockIdx.x] = sh[255];
}

__global__ void scan23(int* __restrict__ rowptr, int* __restrict__ cursor,
                       const int* __restrict__ bsum, int N) {
    __shared__ int red[256];
    int b = blockIdx.x, t = threadIdx.x;
    int s = 0;
    for (int i = t; i < b; i += 256) s += bsum[i];
    red[t] = s;
    __syncthreads();
    for (int off = 128; off; off >>= 1) {
        if (t < off) red[t] += red[t + off];
        __syncthreads();
    }
    int base = red[0];
    int idx = b * 256 + t;
    if (idx >= N) return;
    int v = rowptr[idx + 1] + base;
    rowptr[idx + 1] = v;
    if (idx + 1 < N) cursor[idx + 1] = v;
    if (idx == 0) { rowptr[0] = 0; cursor[0] = 0; }
}

__global__ void scatter_edges(const int* __restrict__ src, const int* __restrict__ dst,
                              int* __restrict__ cursor, int* __restrict__ col, int E) {
    int e = blockIdx.x * blockDim.x + threadIdx.x;
    if (e >= E) return;
    int pos = atomicAdd(&cursor[dst[e]], 1);
    col[pos] = src[e];
}

// ---------------------------------------------------------------------------
// GEMM (bf16 in / bf16 out / single-bf16 weights): Y = f(A) @ W + bias.
// Template: SUBS = row-subtiles, WAVES = launch_bounds min-waves/EU.
// GATHER: r2/r7-verified structure (BM=128, quad-per-row, 8 rows serial,
//   VGPR 48, 56us). FLOOR EVIDENCE: five schedule variants (r2-r7) all
//   land 55-66us with FETCH pinned ~67MB -> random-256B L2/L3 path is
//   saturated; random graph = no locality left. FROZEN.
// POOL: h2 feeds only the per-graph segment-sum. Register run accumulator
//   per t (rows monotone, batch sorted), one global fp32 atomic per
//   segment transition (r9: verified, gemm4 FETCH 13MB / WRITE 1.4MB).
// BNA (r10-r12): SUBS=4 (BM=64). Per-thread register state (b-frags +
//   a-dbuf + acc) is BM-independent -> identical codegen; grid doubles to
//   1563 = 6.1 blocks/CU (was 3.05) -> ~2x waves/CU via GRID, not
//   launch_bounds (r3/r6 lesson: LB caps collapse the schedule; grid
//   scaling doesn't). B re-reads 25->50MB, L2-resident broadcast, noise.
//   (r10 lost to GPUAcquisitionTimeout, r11 to container failure;
//   resubmitted unchanged — downside bounded at r9's 382us by identical
//   per-thread codegen.)
// STATS: fp32 col sum/sumsq via shfl+atomics.
// ---------------------------------------------------------------------------
template <bool RELU, bool BNA, bool STATS, bool GATHER, bool POOL, int SUBS, int WAVES>
__global__ __launch_bounds__(256, WAVES) void gemm128(const ushort_t* __restrict__ A,
                                                  const ushort_t* __restrict__ Bp,
                                                  const float* __restrict__ bias,
                                                  const float* __restrict__ stats_in,
                                                  const float* __restrict__ gamma,
                                                  const float* __restrict__ beta,
                                                  ushort_t* __restrict__ Y,
                                                  float* __restrict__ stats,
                                                  const int* __restrict__ rowptr,
                                                  const int* __restrict__ col,
                                                  const int* __restrict__ batch,
                                                  float* __restrict__ pooled,
                                                  int Nrows) {
    // GATHER: SUBS*16 rows * 256B tile.  POOL: bnps(256f)+bidl(SUBS*16 i).
    __shared__ __align__(16) uint_t smem[GATHER ? SUBS * 16 * 64 : (POOL ? 384 : 256)];
    float* bnps = (float*)smem;
    int wave = threadIdx.x >> 6, lane = threadIdx.x & 63;
    int quad = lane >> 4, l16 = lane & 15;
    int rbase = blockIdx.x * (SUBS * 16);

    if (BNA) {
        if (threadIdx.x < 128) {
            int j = threadIdx.x;
            float s = stats_in[j], ss = stats_in[128 + j];
            float inv_n = 1.0f / (float)Nrows;
            float mu = s * inv_n;
            float var = fmaxf(ss * inv_n - mu * mu, 0.f);
            float sc = gamma[j] * rsqrtf(var + 1e-5f);
            bnps[j] = sc;
            bnps[128 + j] = beta[j] - mu * sc;
        }
    }
    if (POOL) {
        int* bidl = (int*)(smem + 256);
        if (threadIdx.x < SUBS * 16) {
            int rr = rbase + threadIdx.x;
            bidl[threadIdx.x] = (rr < Nrows) ? batch[rr] : 0;
        }
    }
    if (BNA || POOL) __syncthreads();

    // ---- hoist this wave's 8 B-frags (issue before gather: overlaps) ----
    const short8* bp = (const short8*)Bp;
    short8 b[4][2];
#pragma unroll
    for (int c = 0; c < 4; ++c)
#pragma unroll
        for (int t = 0; t < 2; ++t)
            b[c][t] = bp[(c * 8 + wave * 2 + t) * 64 + lane];
    float bsv[2] = { bias[(wave * 2) * 16 + l16], bias[(wave * 2 + 1) * 16 + l16] };

    if (GATHER) {
        // ---- phase 1: CSR gather, one row per quad, SUBS rows serial ----
        const uint4* hp4 = (const uint4*)A;          // 16B units, 16 per row
        int row0 = (wave * 4 + quad) * SUBS;         // this quad's first row
        int st = 0, en = 0;
        {
            int g0 = rbase + row0;
            if (g0 < Nrows) { st = rowptr[g0]; en = rowptr[g0 + 1]; }
        }
        for (int it = 0; it < SUBS; ++it) {
            int r = row0 + it;                       // block-local row
            int grow = rbase + r;
            // prefetch next row's bounds (overlaps this row's edge loop)
            int stn = 0, enn = 0;
            if (it + 1 < SUBS) {
                int g2 = grow + 1;
                if (g2 < Nrows) { stn = rowptr[g2]; enn = rowptr[g2 + 1]; }
            }
            float acc[8] = {0.f, 0.f, 0.f, 0.f, 0.f, 0.f, 0.f, 0.f};
            if (grow < Nrows) {
                uint4 sv = hp4[(size_t)grow * 16 + l16];    // self term
                float2 f0 = upk(sv.x), f1 = upk(sv.y), f2 = upk(sv.z), f3 = upk(sv.w);
                acc[0] = f0.x; acc[1] = f0.y; acc[2] = f1.x; acc[3] = f1.y;
                acc[4] = f2.x; acc[5] = f2.y; acc[6] = f3.x; acc[7] = f3.y;
                int e = st;
                for (; e + 4 <= en; e += 4) {
                    int s0 = col[e], s1 = col[e + 1], s2 = col[e + 2], s3 = col[e + 3];
                    uint4 v0 = hp4[(size_t)s0 * 16 + l16];
                    uint4 v1 = hp4[(size_t)s1 * 16 + l16];
                    uint4 v2 = hp4[(size_t)s2 * 16 + l16];
                    uint4 v3 = hp4[(size_t)s3 * 16 + l16];
                    float2 a0, a1, a2, a3;
                    a0 = upk(v0.x); a1 = upk(v1.x); a2 = upk(v2.x); a3 = upk(v3.x);
                    acc[0] += a0.x + a1.x + a2.x + a3.x;
                    acc[1] += a0.y + a1.y + a2.y + a3.y;
                    a0 = upk(v0.y); a1 = upk(v1.y); a2 = upk(v2.y); a3 = upk(v3.y);
                    acc[2] += a0.x + a1.x + a2.x + a3.x;
                    acc[3] += a0.y + a1.y + a2.y + a3.y;
                    a0 = upk(v0.z); a1 = upk(v1.z); a2 = upk(v2.z); a3 = upk(v3.z);
                    acc[4] += a0.x + a1.x + a2.x + a3.x;
                    acc[5] += a0.y + a1.y + a2.y + a3.y;
                    a0 = upk(v0.w); a1 = upk(v1.w); a2 = upk(v2.w); a3 = upk(v3.w);
                    acc[6] += a0.x + a1.x + a2.x + a3.x;
                    acc[7] += a0.y + a1.y + a2.y + a3.y;
                }
                for (; e < en; ++e) {
                    uint4 v = hp4[(size_t)col[e] * 16 + l16];
                    float2 a0 = upk(v.x), a1 = upk(v.y), a2 = upk(v.z), a3 = upk(v.w);
                    acc[0] += a0.x; acc[1] += a0.y; acc[2] += a1.x; acc[3] += a1.y;
                    acc[4] += a2.x; acc[5] += a2.y; acc[6] += a3.x; acc[7] += a3.y;
                }
            }
            uint4 pk;
            pk.x = (uint_t)f2bf(acc[0]) | ((uint_t)f2bf(acc[1]) << 16);
            pk.y = (uint_t)f2bf(acc[2]) | ((uint_t)f2bf(acc[3]) << 16);
            pk.z = (uint_t)f2bf(acc[4]) | ((uint_t)f2bf(acc[5]) << 16);
            pk.w = (uint_t)f2bf(acc[6]) | ((uint_t)f2bf(acc[7]) << 16);
            ((uint4*)smem)[(r << 4) | (l16 ^ (r & 7))] = pk;   // swizzled b128
            st = stn; en = enn;
        }
        __syncthreads();
    }

    float cs[2] = {0.f, 0.f}, css[2] = {0.f, 0.f};
    float runP[2] = {0.f, 0.f};            // POOL run accumulators
    int segP[2] = {-1, -1};
    short8 a[2][4];   // double buffer (global path only)

    if (!GATHER) {
        // prefetch sub 0
        int arow = rbase + l16;
        if (arow < Nrows) {
            const short8* ap = (const short8*)(A + (size_t)arow * 128);
#pragma unroll
            for (int c = 0; c < 4; ++c) a[0][c] = ap[c * 4 + quad];
        } else {
#pragma unroll
            for (int c = 0; c < 4; ++c) a[0][c] = (short8)0;
        }
    }

    const short8* alds = (const short8*)smem;

#pragma unroll 2
    for (int sub = 0; sub < SUBS; ++sub) {
        short8 af[4];
        if (GATHER) {
            int r = sub * 16 + l16;
#pragma unroll
            for (int c = 0; c < 4; ++c)
                af[c] = alds[(r << 4) | (((c << 2) | quad) ^ (l16 & 7))];
        } else {
            int cur = sub & 1, nxt = cur ^ 1;
            if (sub + 1 < SUBS) {
                int arow = rbase + (sub + 1) * 16 + l16;
                if (arow < Nrows) {
                    const short8* ap = (const short8*)(A + (size_t)arow * 128);
#pragma unroll
                    for (int c = 0; c < 4; ++c) a[nxt][c] = ap[c * 4 + quad];
                } else {
#pragma unroll
                    for (int c = 0; c < 4; ++c) a[nxt][c] = (short8)0;
                }
            }
#pragma unroll
            for (int c = 0; c < 4; ++c) {
                if (BNA) {
                    int cbase = c * 32 + quad * 8;
#pragma unroll
                    for (int i = 0; i < 8; ++i) {
                        float x = bf2f((ushort_t)a[cur][c][i]);
                        x = fmaxf(x * bnps[cbase + i] + bnps[128 + cbase + i], 0.f);
                        af[c][i] = (short)f2bf(x);
                    }
                } else {
                    af[c] = a[cur][c];
                }
            }
        }
        f32x4 acc[2] = {};
#pragma unroll
        for (int c = 0; c < 4; ++c)
#pragma unroll
            for (int t = 0; t < 2; ++t)
                acc[t] = __builtin_amdgcn_mfma_f32_16x16x32_bf16(af[c], b[c][t], acc[t], 0, 0, 0);
#pragma unroll
        for (int t = 0; t < 2; ++t) {
            int colj = (wave * 2 + t) * 16 + l16;
#pragma unroll
            for (int i = 0; i < 4; ++i) {
                int row = rbase + sub * 16 + quad * 4 + i;
                if (row < Nrows) {
                    float v = acc[t][i] + bsv[t];
                    if (RELU) v = fmaxf(v, 0.f);
                    if (POOL) {
                        // rows visit segments monotonically (sorted batch):
                        // register run accumulator, flush on transition.
                        int seg = ((int*)(smem + 256))[row - rbase];
                        if (seg != segP[t]) {
                            if (segP[t] >= 0)
                                unsafeAtomicAdd(&pooled[(size_t)segP[t] * 128 + colj], runP[t]);
                            segP[t] = seg;
                            runP[t] = 0.f;
                        }
                        runP[t] += v;
                    } else {
                        Y[(size_t)row * 128 + colj] = f2bf(v);
                    }
                    if (STATS) { cs[t] += v; css[t] += v * v; }
                }
            }
        }
    }
    if (POOL) {
#pragma unroll
        for (int t = 0; t < 2; ++t) {
            if (segP[t] >= 0) {
                int colj = (wave * 2 + t) * 16 + l16;
                unsafeAtomicAdd(&pooled[(size_t)segP[t] * 128 + colj], runP[t]);
            }
        }
    }
    if (STATS) {
#pragma unroll
        for (int t = 0; t < 2; ++t) {
            float s = cs[t], q = css[t];
            s += __shfl_xor(s, 16); q += __shfl_xor(q, 16);
            s += __shfl_xor(s, 32); q += __shfl_xor(q, 32);
            if (quad == 0) {
                int colj = (wave * 2 + t) * 16 + l16;
                unsafeAtomicAdd(&stats[colj], s);
                unsafeAtomicAdd(&stats[128 + colj], q);
            }
        }
    }
}

// ---------------------------------------------------------------------------
// Head: read fp32 pooled (produced by gemm4's fused pool) + MLP + concat +
// final log_softmax (fp32 math throughout)
// ---------------------------------------------------------------------------
__global__ void head_kernel(const float* __restrict__ pooled,
                            const float* __restrict__ code_emb,
                            const float* __restrict__ l1w, const float* __restrict__ l1b,
                            const float* __restrict__ l2w, const float* __restrict__ l2b,
                            const float* __restrict__ finw, const float* __restrict__ finb,
                            float* __restrict__ out) {
    int g = blockIdx.x, j = threadIdx.x;   // 128 threads
    __shared__ float pb[128], t[128], v[128], lg[2];
    pb[j] = pooled[(size_t)g * 128 + j];
    __syncthreads();
    float acc = l1b[j];
    for (int k = 0; k < 128; ++k) acc += pb[k] * l1w[k * 128 + j];
    t[j] = fmaxf(acc, 0.f);
    __syncthreads();
    if (j < 64) {
        float a2 = l2b[j];
        for (int k = 0; k < 128; ++k) a2 += t[k] * l2w[k * 64 + j];
        v[64 + j] = a2;                       // trans_emb
        v[j] = code_emb[(size_t)g * 64 + j];  // code_emb
    }
    __syncthreads();
    if (j < 2) {
        float a3 = finb[j];
        for (int k = 0; k < 128; ++k) a3 += v[k] * finw[k * 2 + j];
        lg[j] = a3;
    }
    __syncthreads();
    if (j == 0) {
        float a = lg[0], b = lg[1];
        float m = fmaxf(a, b);
        float lse = m + logf(expf(a - m) + expf(b - m));
        out[g * 2 + 0] = a - lse;
        out[g * 2 + 1] = b - lse;
    }
}

// ---------------------------------------------------------------------------

extern "C" void kernel_launch(void* const* d_in, const int* in_sizes, int n_in,
                              void* d_out, int out_size, void* d_ws, size_t ws_size,
                              hipStream_t stream) {
    (void)n_in; (void)out_size; (void)ws_size;
    const float* x     = (const float*)d_in[0];
    const int*   ei    = (const int*)d_in[1];
    const int*   batch = (const int*)d_in[2];
    const float* cx    = (const float*)d_in[3];
    const float* c1w1  = (const float*)d_in[4];
    const float* c1b1  = (const float*)d_in[5];
    const float* c1g   = (const float*)d_in[6];
    const float* c1be  = (const float*)d_in[7];
    const float* c1w2  = (const float*)d_in[8];
    const float* c1b2  = (const float*)d_in[9];
    const float* c2w1  = (const float*)d_in[10];
    const float* c2b1  = (const float*)d_in[11];
    const float* c2g   = (const float*)d_in[12];
    const float* c2be  = (const float*)d_in[13];
    const float* c2w2  = (const float*)d_in[14];
    const float* c2b2  = (const float*)d_in[15];
    const float* gl1w  = (const float*)d_in[16];
    const float* gl1b  = (const float*)d_in[17];
    const float* gl2w  = (const float*)d_in[18];
    const float* gl2b  = (const float*)d_in[19];
    const float* fc1w  = (const float*)d_in[20];
    const float* fc1b  = (const float*)d_in[21];
    const float* fc2w  = (const float*)d_in[22];
    const float* fc2b  = (const float*)d_in[23];
    const float* fc3w  = (const float*)d_in[24];
    const float* fc3b  = (const float*)d_in[25];
    const float* finw  = (const float*)d_in[26];
    const float* finb  = (const float*)d_in[27];

    const int N = in_sizes[0] / 128;
    const int E = in_sizes[1] / 2;
    const int G = in_sizes[3] / 128;
    const int* src = ei;
    const int* dst = ei + E;

    // workspace layout (16B-aligned)
    ushort_t* bufA = (ushort_t*)d_ws;                  // N*128 bf16
    ushort_t* bufB = bufA + (size_t)N * 128;           // N*128 bf16
    float* code_emb = (float*)(bufB + (size_t)N * 128); // G*64
    float* statsA   = code_emb + (size_t)G * 64;       // 256
    float* statsB   = statsA + 256;                    // 256
    float* pooled   = statsB + 256;                    // G*128 fp32
    ushort_t* packW = (ushort_t*)(pooled + (size_t)G * 128); // 4*16384 ushorts
    int* rowptr = (int*)(packW + 4 * 16384);           // N+1
    int* tmp    = rowptr + (N + 1);                    // N+1 (deg, then cursor)
    int* bsum   = tmp + (N + 1);                       // 512
    int* col    = bsum + 512;                          // E

    const int gmm  = (N + 127) / 128;                  // BM=128 grid (gather)
    const int gm64 = (N + 63) / 64;                    // BM=64 grid (BNA/POOL)
    const int nb   = (N + 255) / 256;                  // scan chunks (<=512)

    const int n2    = N * 64;
    const int np    = G * 128;
    const int cvtB  = (n2 + 255) / 256;
    int initB = (N + 1 + 255) / 256;
    const int initB2 = (np + 255) / 256;
    if (initB2 > initB) initB = initB2;
    const int prepB = cvtB + initB + 256 + G;

    // ---- prep: cvt(x->bf16) + zero(deg,stats,pooled) + pack_w + code ----
    prep<<<prepB, 256, 0, stream>>>((const float2*)x, (uint_t*)bufB, n2, cvtB,
                                    tmp, N + 1, statsA, pooled, np, initB,
                                    c1w1, c1w2, c2w1, c2w2, packW,
                                    cx, fc1w, fc1b, fc2w, fc2b, fc3w, fc3b, code_emb);

    // ---- CSR build ----
    hist_dst<<<(E + 255) / 256, 256, 0, stream>>>(dst, tmp, E);
    scan1<<<nb, 256, 0, stream>>>(tmp, rowptr, bsum, N);
    scan23<<<nb, 256, 0, stream>>>(rowptr, tmp, bsum, N);
    scatter_edges<<<(E + 255) / 256, 256, 0, stream>>>(src, dst, tmp, col, E);

    // ---- conv1 (gather fused into gemm1; BNA gemm2 at BM=64) ----
    gemm128<false, false, true, true, false, 8, 3><<<gmm, 256, 0, stream>>>(
        bufB, packW, c1b1, nullptr, nullptr, nullptr, bufA, statsA,
        rowptr, col, nullptr, nullptr, N);                                      // y1 + stats
    gemm128<true, true, false, false, false, 4, 2><<<gm64, 256, 0, stream>>>(
        bufA, packW + 16384, c1b2, statsA, c1g, c1be, bufB, nullptr,
        nullptr, nullptr, nullptr, nullptr, N);                                 // h1 (BN fused)

    // ---- conv2 (gather gemm3; gemm4 = BNA+POOL at BM=64) ----
    gemm128<false, false, true, true, false, 8, 3><<<gmm, 256, 0, stream>>>(
        bufB, packW + 2 * 16384, c2b1, nullptr, nullptr, nullptr, bufA, statsB,
        rowptr, col, nullptr, nullptr, N);                                      // y2 + stats
    gemm128<true, true, false, false, true, 4, 2><<<gm64, 256, 0, stream>>>(
        bufA, packW + 3 * 16384, c2b2, statsB, c2g, c2be, bufB, nullptr,
        nullptr, nullptr, batch, pooled, N);                                    // pooled += h2

    head_kernel<<<G, 128, 0, stream>>>(pooled, code_emb,
                                       gl1w, gl1b, gl2w, gl2b, finw, finb,
                                       (float*)d_out);
}

// Round 13
// 381.179 us; speedup vs baseline: 1.0073x; 1.0073x over previous
//
#include <hip/hip_runtime.h>

typedef unsigned short ushort_t;
typedef unsigned int uint_t;
typedef __attribute__((ext_vector_type(8))) short short8;
typedef __attribute__((ext_vector_type(4))) float f32x4;

__device__ __forceinline__ float bf2f(ushort_t u) {
    union { unsigned u; float f; } c; c.u = ((unsigned)u) << 16; return c.f;
}
__device__ __forceinline__ ushort_t f2bf(float f) {
    union { float f; unsigned u; } c; c.f = f;
    unsigned u = c.u;
    u += 0x7fffu + ((u >> 16) & 1u);   // RNE
    return (ushort_t)(u >> 16);
}
__device__ __forceinline__ float2 upk(uint_t u) {
    float2 r; r.x = bf2f((ushort_t)(u & 0xffffu)); r.y = bf2f((ushort_t)(u >> 16));
    return r;
}

// ---------------------------------------------------------------------------
// PREP (fused, independent sections partitioned by blockIdx):
//   [0, cvtB)              : x fp32 -> bf16 (2 elems/thread)
//   [cvtB, cvtB+initB)     : zero deg[N+1] + stats[512] + pooled[G*128]
//   [+initB, +initB+256)   : pack 4 weight matrices into MFMA B-frag bf16
//   [.., +G)               : code-branch per-graph MLP + log_softmax
// ---------------------------------------------------------------------------
__global__ __launch_bounds__(256) void prep(
    const float2* __restrict__ x2, uint_t* __restrict__ xbf, int n2, int cvtB,
    int* __restrict__ deg, int ni, float* __restrict__ stats0,
    float* __restrict__ pool0, int np, int initB,
    const float* __restrict__ w0, const float* __restrict__ w1,
    const float* __restrict__ w2, const float* __restrict__ w3,
    ushort_t* __restrict__ packW,
    const float* __restrict__ cx,
    const float* __restrict__ cw1, const float* __restrict__ cb1,
    const float* __restrict__ cw2, const float* __restrict__ cb2,
    const float* __restrict__ cw3, const float* __restrict__ cb3,
    float* __restrict__ code_emb) {
    __shared__ float xb[128], h[128];
    int blk = blockIdx.x, tid = threadIdx.x;

    if (blk < cvtB) {                      // ---- cvt ----
        int i = blk * 256 + tid;
        if (i < n2) {
            float2 v = x2[i];
            xbf[i] = (uint_t)f2bf(v.x) | ((uint_t)f2bf(v.y) << 16);
        }
        return;
    }
    blk -= cvtB;
    if (blk < initB) {                     // ---- init ----
        int i = blk * 256 + tid;
        if (i < ni) deg[i] = 0;
        if (i < 512) stats0[i] = 0.f;
        if (i < np) pool0[i] = 0.f;
        return;
    }
    blk -= initB;
    if (blk < 256) {                       // ---- pack_w ----
        int id = blk * 256 + tid;          // 4*16384 total
        int m = id >> 14, r = id & 16383;
        const float* w = (m == 0) ? w0 : (m == 1) ? w1 : (m == 2) ? w2 : w3;
        int i = r & 7, lane = (r >> 3) & 63, ct = (r >> 9) & 7, ch = r >> 12;
        int k = ch * 32 + ((lane >> 4) << 3) + i;
        int n = ct * 16 + (lane & 15);
        packW[m * 16384 + r] = f2bf(w[k * 128 + n]);
        return;
    }
    blk -= 256;
    {                                      // ---- code branch (g = blk) ----
        int g = blk, j = tid;
        if (j < 128) xb[j] = cx[(size_t)g * 128 + j];
        __syncthreads();
        float acc = 0.f;
        if (j < 128) {
            acc = cb1[j];
            for (int k = 0; k < 128; ++k) acc += xb[k] * cw1[k * 128 + j];
        }
        __syncthreads();
        if (j < 128) h[j] = fmaxf(acc, 0.f);
        __syncthreads();
        if (j < 128) {
            acc = cb2[j];
            for (int k = 0; k < 128; ++k) acc += h[k] * cw2[k * 128 + j];
        }
        __syncthreads();
        if (j < 128) xb[j] = fmaxf(acc, 0.f);
        __syncthreads();
        if (j < 64) {
            float o = cb3[j];
            for (int k = 0; k < 128; ++k) o += xb[k] * cw3[k * 64 + j];
            float m = o;
            for (int off = 32; off; off >>= 1) m = fmaxf(m, __shfl_xor(m, off));
            float e = expf(o - m), s = e;
            for (int off = 32; off; off >>= 1) s += __shfl_xor(s, off);
            float lse = m + logf(s);
            code_emb[(size_t)g * 64 + j] = o - lse;
        }
    }
}

// ---------------------------------------------------------------------------
// CSR build: histogram -> per-chunk scan -> (scan bsum + apply, merged) ->
// scatter
// ---------------------------------------------------------------------------
__global__ void hist_dst(const int* __restrict__ dst, int* __restrict__ deg, int E) {
    int e = blockIdx.x * blockDim.x + threadIdx.x;
    if (e < E) atomicAdd(&deg[dst[e]], 1);
}

__global__ void scan1(const int* __restrict__ deg, int* __restrict__ rowptr,
                      int* __restrict__ bsum, int N) {
    __shared__ int sh[256];
    int t = threadIdx.x, idx = blockIdx.x * 256 + t;
    sh[t] = (idx < N) ? deg[idx] : 0;
    __syncthreads();
    for (int off = 1; off < 256; off <<= 1) {
        int v = (t >= off) ? sh[t - off] : 0;
        __syncthreads();
        sh[t] += v;
        __syncthreads();
    }
    if (idx < N) rowptr[idx + 1] = sh[t];
    if (t == 255) bsum[blockIdx.x] = sh[255];
}

__global__ void scan23(int* __restrict__ rowptr, int* __restrict__ cursor,
                       const int* __restrict__ bsum, int N) {
    __shared__ int red[256];
    int b = blockIdx.x, t = threadIdx.x;
    int s = 0;
    for (int i = t; i < b; i += 256) s += bsum[i];
    red[t] = s;
    __syncthreads();
    for (int off = 128; off; off >>= 1) {
        if (t < off) red[t] += red[t + off];
        __syncthreads();
    }
    int base = red[0];
    int idx = b * 256 + t;
    if (idx >= N) return;
    int v = rowptr[idx + 1] + base;
    rowptr[idx + 1] = v;
    if (idx + 1 < N) cursor[idx + 1] = v;
    if (idx == 0) { rowptr[0] = 0; cursor[0] = 0; }
}

__global__ void scatter_edges(const int* __restrict__ src, const int* __restrict__ dst,
                              int* __restrict__ cursor, int* __restrict__ col, int E) {
    int e = blockIdx.x * blockDim.x + threadIdx.x;
    if (e >= E) return;
    int pos = atomicAdd(&cursor[dst[e]], 1);
    col[pos] = src[e];
}

// ---------------------------------------------------------------------------
// GEMM (bf16 in / bf16 out / single-bf16 weights): Y = f(A) @ W + bias.
// Template: SUBS = row-subtiles, WAVES = launch_bounds min-waves/EU.
// GATHER: r2/r7-verified structure (BM=128, quad-per-row, 8 rows serial,
//   VGPR 48, 56us). FLOOR EVIDENCE: five schedule variants (r2-r7,
//   occupancy 23-43%, three dataflows) all land 55-66us with FETCH pinned
//   ~67MB -> random-256B L2-miss path saturated (~1.2 TB/s beyond-L2;
//   25.6MB table > 4MB/XCD L2). FROZEN.
// POOL: h2 feeds only the per-graph segment-sum. Register run accumulator
//   per t (rows monotone, batch sorted), one global fp32 atomic per
//   segment transition (r9: verified, gemm4 FETCH 13MB / WRITE 1.4MB).
// BNA: SUBS=8/BM=128/LB(256,2) — r12 A/B'd SUBS=4 (2x grid occupancy,
//   identical codegen): 384.0 vs r9's 381.9 = within noise -> BNA gemms
//   are latency-floored; r9 config locked in as measured minimum.
// STATS: fp32 col sum/sumsq via shfl+atomics.
// ---------------------------------------------------------------------------
template <bool RELU, bool BNA, bool STATS, bool GATHER, bool POOL, int SUBS, int WAVES>
__global__ __launch_bounds__(256, WAVES) void gemm128(const ushort_t* __restrict__ A,
                                                  const ushort_t* __restrict__ Bp,
                                                  const float* __restrict__ bias,
                                                  const float* __restrict__ stats_in,
                                                  const float* __restrict__ gamma,
                                                  const float* __restrict__ beta,
                                                  ushort_t* __restrict__ Y,
                                                  float* __restrict__ stats,
                                                  const int* __restrict__ rowptr,
                                                  const int* __restrict__ col,
                                                  const int* __restrict__ batch,
                                                  float* __restrict__ pooled,
                                                  int Nrows) {
    // GATHER: SUBS*16 rows * 256B tile.  POOL: bnps(256f)+bidl(128i).
    __shared__ __align__(16) uint_t smem[GATHER ? SUBS * 16 * 64 : (POOL ? 384 : 256)];
    float* bnps = (float*)smem;
    int wave = threadIdx.x >> 6, lane = threadIdx.x & 63;
    int quad = lane >> 4, l16 = lane & 15;
    int rbase = blockIdx.x * (SUBS * 16);

    if (BNA) {
        if (threadIdx.x < 128) {
            int j = threadIdx.x;
            float s = stats_in[j], ss = stats_in[128 + j];
            float inv_n = 1.0f / (float)Nrows;
            float mu = s * inv_n;
            float var = fmaxf(ss * inv_n - mu * mu, 0.f);
            float sc = gamma[j] * rsqrtf(var + 1e-5f);
            bnps[j] = sc;
            bnps[128 + j] = beta[j] - mu * sc;
        }
    }
    if (POOL) {
        int* bidl = (int*)(smem + 256);
        if (threadIdx.x < SUBS * 16) {
            int rr = rbase + threadIdx.x;
            bidl[threadIdx.x] = (rr < Nrows) ? batch[rr] : 0;
        }
    }
    if (BNA || POOL) __syncthreads();

    // ---- hoist this wave's 8 B-frags (issue before gather: overlaps) ----
    const short8* bp = (const short8*)Bp;
    short8 b[4][2];
#pragma unroll
    for (int c = 0; c < 4; ++c)
#pragma unroll
        for (int t = 0; t < 2; ++t)
            b[c][t] = bp[(c * 8 + wave * 2 + t) * 64 + lane];
    float bsv[2] = { bias[(wave * 2) * 16 + l16], bias[(wave * 2 + 1) * 16 + l16] };

    if (GATHER) {
        // ---- phase 1: CSR gather, one row per quad, SUBS rows serial ----
        const uint4* hp4 = (const uint4*)A;          // 16B units, 16 per row
        int row0 = (wave * 4 + quad) * SUBS;         // this quad's first row
        int st = 0, en = 0;
        {
            int g0 = rbase + row0;
            if (g0 < Nrows) { st = rowptr[g0]; en = rowptr[g0 + 1]; }
        }
        for (int it = 0; it < SUBS; ++it) {
            int r = row0 + it;                       // block-local row
            int grow = rbase + r;
            // prefetch next row's bounds (overlaps this row's edge loop)
            int stn = 0, enn = 0;
            if (it + 1 < SUBS) {
                int g2 = grow + 1;
                if (g2 < Nrows) { stn = rowptr[g2]; enn = rowptr[g2 + 1]; }
            }
            float acc[8] = {0.f, 0.f, 0.f, 0.f, 0.f, 0.f, 0.f, 0.f};
            if (grow < Nrows) {
                uint4 sv = hp4[(size_t)grow * 16 + l16];    // self term
                float2 f0 = upk(sv.x), f1 = upk(sv.y), f2 = upk(sv.z), f3 = upk(sv.w);
                acc[0] = f0.x; acc[1] = f0.y; acc[2] = f1.x; acc[3] = f1.y;
                acc[4] = f2.x; acc[5] = f2.y; acc[6] = f3.x; acc[7] = f3.y;
                int e = st;
                for (; e + 4 <= en; e += 4) {
                    int s0 = col[e], s1 = col[e + 1], s2 = col[e + 2], s3 = col[e + 3];
                    uint4 v0 = hp4[(size_t)s0 * 16 + l16];
                    uint4 v1 = hp4[(size_t)s1 * 16 + l16];
                    uint4 v2 = hp4[(size_t)s2 * 16 + l16];
                    uint4 v3 = hp4[(size_t)s3 * 16 + l16];
                    float2 a0, a1, a2, a3;
                    a0 = upk(v0.x); a1 = upk(v1.x); a2 = upk(v2.x); a3 = upk(v3.x);
                    acc[0] += a0.x + a1.x + a2.x + a3.x;
                    acc[1] += a0.y + a1.y + a2.y + a3.y;
                    a0 = upk(v0.y); a1 = upk(v1.y); a2 = upk(v2.y); a3 = upk(v3.y);
                    acc[2] += a0.x + a1.x + a2.x + a3.x;
                    acc[3] += a0.y + a1.y + a2.y + a3.y;
                    a0 = upk(v0.z); a1 = upk(v1.z); a2 = upk(v2.z); a3 = upk(v3.z);
                    acc[4] += a0.x + a1.x + a2.x + a3.x;
                    acc[5] += a0.y + a1.y + a2.y + a3.y;
                    a0 = upk(v0.w); a1 = upk(v1.w); a2 = upk(v2.w); a3 = upk(v3.w);
                    acc[6] += a0.x + a1.x + a2.x + a3.x;
                    acc[7] += a0.y + a1.y + a2.y + a3.y;
                }
                for (; e < en; ++e) {
                    uint4 v = hp4[(size_t)col[e] * 16 + l16];
                    float2 a0 = upk(v.x), a1 = upk(v.y), a2 = upk(v.z), a3 = upk(v.w);
                    acc[0] += a0.x; acc[1] += a0.y; acc[2] += a1.x; acc[3] += a1.y;
                    acc[4] += a2.x; acc[5] += a2.y; acc[6] += a3.x; acc[7] += a3.y;
                }
            }
            uint4 pk;
            pk.x = (uint_t)f2bf(acc[0]) | ((uint_t)f2bf(acc[1]) << 16);
            pk.y = (uint_t)f2bf(acc[2]) | ((uint_t)f2bf(acc[3]) << 16);
            pk.z = (uint_t)f2bf(acc[4]) | ((uint_t)f2bf(acc[5]) << 16);
            pk.w = (uint_t)f2bf(acc[6]) | ((uint_t)f2bf(acc[7]) << 16);
            ((uint4*)smem)[(r << 4) | (l16 ^ (r & 7))] = pk;   // swizzled b128
            st = stn; en = enn;
        }
        __syncthreads();
    }

    float cs[2] = {0.f, 0.f}, css[2] = {0.f, 0.f};
    float runP[2] = {0.f, 0.f};            // POOL run accumulators
    int segP[2] = {-1, -1};
    short8 a[2][4];   // double buffer (global path only)

    if (!GATHER) {
        // prefetch sub 0
        int arow = rbase + l16;
        if (arow < Nrows) {
            const short8* ap = (const short8*)(A + (size_t)arow * 128);
#pragma unroll
            for (int c = 0; c < 4; ++c) a[0][c] = ap[c * 4 + quad];
        } else {
#pragma unroll
            for (int c = 0; c < 4; ++c) a[0][c] = (short8)0;
        }
    }

    const short8* alds = (const short8*)smem;

#pragma unroll 2
    for (int sub = 0; sub < SUBS; ++sub) {
        short8 af[4];
        if (GATHER) {
            int r = sub * 16 + l16;
#pragma unroll
            for (int c = 0; c < 4; ++c)
                af[c] = alds[(r << 4) | (((c << 2) | quad) ^ (l16 & 7))];
        } else {
            int cur = sub & 1, nxt = cur ^ 1;
            if (sub + 1 < SUBS) {
                int arow = rbase + (sub + 1) * 16 + l16;
                if (arow < Nrows) {
                    const short8* ap = (const short8*)(A + (size_t)arow * 128);
#pragma unroll
                    for (int c = 0; c < 4; ++c) a[nxt][c] = ap[c * 4 + quad];
                } else {
#pragma unroll
                    for (int c = 0; c < 4; ++c) a[nxt][c] = (short8)0;
                }
            }
#pragma unroll
            for (int c = 0; c < 4; ++c) {
                if (BNA) {
                    int cbase = c * 32 + quad * 8;
#pragma unroll
                    for (int i = 0; i < 8; ++i) {
                        float x = bf2f((ushort_t)a[cur][c][i]);
                        x = fmaxf(x * bnps[cbase + i] + bnps[128 + cbase + i], 0.f);
                        af[c][i] = (short)f2bf(x);
                    }
                } else {
                    af[c] = a[cur][c];
                }
            }
        }
        f32x4 acc[2] = {};
#pragma unroll
        for (int c = 0; c < 4; ++c)
#pragma unroll
            for (int t = 0; t < 2; ++t)
                acc[t] = __builtin_amdgcn_mfma_f32_16x16x32_bf16(af[c], b[c][t], acc[t], 0, 0, 0);
#pragma unroll
        for (int t = 0; t < 2; ++t) {
            int colj = (wave * 2 + t) * 16 + l16;
#pragma unroll
            for (int i = 0; i < 4; ++i) {
                int row = rbase + sub * 16 + quad * 4 + i;
                if (row < Nrows) {
                    float v = acc[t][i] + bsv[t];
                    if (RELU) v = fmaxf(v, 0.f);
                    if (POOL) {
                        // rows visit segments monotonically (sorted batch):
                        // register run accumulator, flush on transition.
                        int seg = ((int*)(smem + 256))[row - rbase];
                        if (seg != segP[t]) {
                            if (segP[t] >= 0)
                                unsafeAtomicAdd(&pooled[(size_t)segP[t] * 128 + colj], runP[t]);
                            segP[t] = seg;
                            runP[t] = 0.f;
                        }
                        runP[t] += v;
                    } else {
                        Y[(size_t)row * 128 + colj] = f2bf(v);
                    }
                    if (STATS) { cs[t] += v; css[t] += v * v; }
                }
            }
        }
    }
    if (POOL) {
#pragma unroll
        for (int t = 0; t < 2; ++t) {
            if (segP[t] >= 0) {
                int colj = (wave * 2 + t) * 16 + l16;
                unsafeAtomicAdd(&pooled[(size_t)segP[t] * 128 + colj], runP[t]);
            }
        }
    }
    if (STATS) {
#pragma unroll
        for (int t = 0; t < 2; ++t) {
            float s = cs[t], q = css[t];
            s += __shfl_xor(s, 16); q += __shfl_xor(q, 16);
            s += __shfl_xor(s, 32); q += __shfl_xor(q, 32);
            if (quad == 0) {
                int colj = (wave * 2 + t) * 16 + l16;
                unsafeAtomicAdd(&stats[colj], s);
                unsafeAtomicAdd(&stats[128 + colj], q);
            }
        }
    }
}

// ---------------------------------------------------------------------------
// Head: read fp32 pooled (produced by gemm4's fused pool) + MLP + concat +
// final log_softmax (fp32 math throughout)
// ---------------------------------------------------------------------------
__global__ void head_kernel(const float* __restrict__ pooled,
                            const float* __restrict__ code_emb,
                            const float* __restrict__ l1w, const float* __restrict__ l1b,
                            const float* __restrict__ l2w, const float* __restrict__ l2b,
                            const float* __restrict__ finw, const float* __restrict__ finb,
                            float* __restrict__ out) {
    int g = blockIdx.x, j = threadIdx.x;   // 128 threads
    __shared__ float pb[128], t[128], v[128], lg[2];
    pb[j] = pooled[(size_t)g * 128 + j];
    __syncthreads();
    float acc = l1b[j];
    for (int k = 0; k < 128; ++k) acc += pb[k] * l1w[k * 128 + j];
    t[j] = fmaxf(acc, 0.f);
    __syncthreads();
    if (j < 64) {
        float a2 = l2b[j];
        for (int k = 0; k < 128; ++k) a2 += t[k] * l2w[k * 64 + j];
        v[64 + j] = a2;                       // trans_emb
        v[j] = code_emb[(size_t)g * 64 + j];  // code_emb
    }
    __syncthreads();
    if (j < 2) {
        float a3 = finb[j];
        for (int k = 0; k < 128; ++k) a3 += v[k] * finw[k * 2 + j];
        lg[j] = a3;
    }
    __syncthreads();
    if (j == 0) {
        float a = lg[0], b = lg[1];
        float m = fmaxf(a, b);
        float lse = m + logf(expf(a - m) + expf(b - m));
        out[g * 2 + 0] = a - lse;
        out[g * 2 + 1] = b - lse;
    }
}

// ---------------------------------------------------------------------------

extern "C" void kernel_launch(void* const* d_in, const int* in_sizes, int n_in,
                              void* d_out, int out_size, void* d_ws, size_t ws_size,
                              hipStream_t stream) {
    (void)n_in; (void)out_size; (void)ws_size;
    const float* x     = (const float*)d_in[0];
    const int*   ei    = (const int*)d_in[1];
    const int*   batch = (const int*)d_in[2];
    const float* cx    = (const float*)d_in[3];
    const float* c1w1  = (const float*)d_in[4];
    const float* c1b1  = (const float*)d_in[5];
    const float* c1g   = (const float*)d_in[6];
    const float* c1be  = (const float*)d_in[7];
    const float* c1w2  = (const float*)d_in[8];
    const float* c1b2  = (const float*)d_in[9];
    const float* c2w1  = (const float*)d_in[10];
    const float* c2b1  = (const float*)d_in[11];
    const float* c2g   = (const float*)d_in[12];
    const float* c2be  = (const float*)d_in[13];
    const float* c2w2  = (const float*)d_in[14];
    const float* c2b2  = (const float*)d_in[15];
    const float* gl1w  = (const float*)d_in[16];
    const float* gl1b  = (const float*)d_in[17];
    const float* gl2w  = (const float*)d_in[18];
    const float* gl2b  = (const float*)d_in[19];
    const float* fc1w  = (const float*)d_in[20];
    const float* fc1b  = (const float*)d_in[21];
    const float* fc2w  = (const float*)d_in[22];
    const float* fc2b  = (const float*)d_in[23];
    const float* fc3w  = (const float*)d_in[24];
    const float* fc3b  = (const float*)d_in[25];
    const float* finw  = (const float*)d_in[26];
    const float* finb  = (const float*)d_in[27];

    const int N = in_sizes[0] / 128;
    const int E = in_sizes[1] / 2;
    const int G = in_sizes[3] / 128;
    const int* src = ei;
    const int* dst = ei + E;

    // workspace layout (16B-aligned)
    ushort_t* bufA = (ushort_t*)d_ws;                  // N*128 bf16
    ushort_t* bufB = bufA + (size_t)N * 128;           // N*128 bf16
    float* code_emb = (float*)(bufB + (size_t)N * 128); // G*64
    float* statsA   = code_emb + (size_t)G * 64;       // 256
    float* statsB   = statsA + 256;                    // 256
    float* pooled   = statsB + 256;                    // G*128 fp32
    ushort_t* packW = (ushort_t*)(pooled + (size_t)G * 128); // 4*16384 ushorts
    int* rowptr = (int*)(packW + 4 * 16384);           // N+1
    int* tmp    = rowptr + (N + 1);                    // N+1 (deg, then cursor)
    int* bsum   = tmp + (N + 1);                       // 512
    int* col    = bsum + 512;                          // E

    const int gmm = (N + 127) / 128;                   // BM=128 grid
    const int nb  = (N + 255) / 256;                   // scan chunks (<=512)

    const int n2    = N * 64;
    const int np    = G * 128;
    const int cvtB  = (n2 + 255) / 256;
    int initB = (N + 1 + 255) / 256;
    const int initB2 = (np + 255) / 256;
    if (initB2 > initB) initB = initB2;
    const int prepB = cvtB + initB + 256 + G;

    // ---- prep: cvt(x->bf16) + zero(deg,stats,pooled) + pack_w + code ----
    prep<<<prepB, 256, 0, stream>>>((const float2*)x, (uint_t*)bufB, n2, cvtB,
                                    tmp, N + 1, statsA, pooled, np, initB,
                                    c1w1, c1w2, c2w1, c2w2, packW,
                                    cx, fc1w, fc1b, fc2w, fc2b, fc3w, fc3b, code_emb);

    // ---- CSR build ----
    hist_dst<<<(E + 255) / 256, 256, 0, stream>>>(dst, tmp, E);
    scan1<<<nb, 256, 0, stream>>>(tmp, rowptr, bsum, N);
    scan23<<<nb, 256, 0, stream>>>(rowptr, tmp, bsum, N);
    scatter_edges<<<(E + 255) / 256, 256, 0, stream>>>(src, dst, tmp, col, E);

    // ---- conv1 (gather fused into gemm1) ----
    gemm128<false, false, true, true, false, 8, 3><<<gmm, 256, 0, stream>>>(
        bufB, packW, c1b1, nullptr, nullptr, nullptr, bufA, statsA,
        rowptr, col, nullptr, nullptr, N);                                      // y1 + stats
    gemm128<true, true, false, false, false, 8, 2><<<gmm, 256, 0, stream>>>(
        bufA, packW + 16384, c1b2, statsA, c1g, c1be, bufB, nullptr,
        nullptr, nullptr, nullptr, nullptr, N);                                 // h1 (BN fused)

    // ---- conv2 (gather fused into gemm3; gemm4 pools instead of writing) ----
    gemm128<false, false, true, true, false, 8, 3><<<gmm, 256, 0, stream>>>(
        bufB, packW + 2 * 16384, c2b1, nullptr, nullptr, nullptr, bufA, statsB,
        rowptr, col, nullptr, nullptr, N);                                      // y2 + stats
    gemm128<true, true, false, false, true, 8, 2><<<gmm, 256, 0, stream>>>(
        bufA, packW + 3 * 16384, c2b2, statsB, c2g, c2be, bufB, nullptr,
        nullptr, nullptr, batch, pooled, N);                                    // pooled += h2

    head_kernel<<<G, 128, 0, stream>>>(pooled, code_emb,
                                       gl1w, gl1b, gl2w, gl2b, finw, finb,
                                       (float*)d_out);
}